// Round 4
// baseline (69.893 us; speedup 1.0000x reference)
//
#include <hip/hip_runtime.h>

// CubicalEcc: x [8,3,224,224] f32 -> ecc [8,3,32] f32  — SINGLE KERNEL.
// Per-pixel Euler increment: every cell (vertex/edge/face) is owned by its
// argmin incident pixel (ties by row-major memory order; exact with ties).
// chi(t) = sum_p [v_p <= t] * delta_p,  delta_p = 1 + nV(p) - nE(p).
// "p beats q": v_p < v_q if q earlier in row-major order, v_p <= v_q if later;
// out-of-image q = +inf. One block per image: LDS signed histogram of first
// bins -> prefix sum -> 32 output floats. No workspace, no 2nd dispatch.

#define HH 224
#define WW 224
#define STEPS 32
#define NBC 24           // 8*3 images
#define NW 16            // waves per block (1024 threads)
#define ROWS_PER_WAVE 14 // 16*14 = 224
#define HPAD 33          // hist stride: spreads bin k of wave w across banks

// smallest k in [0,32) with v <= t_k, t_k = -2 + k*(4/31); 32 => never counted
__device__ __forceinline__ int bin_of(float v) {
    int k = (int)ceilf(fmaf(v, 7.75f, 15.5f));  // (v+2)*31/4
    return max(0, min(32, k));
}

__global__ __launch_bounds__(1024) void ecc_all(const float* __restrict__ x,
                                                float* __restrict__ out) {
    __shared__ int hist[NW * HPAD];
    __shared__ int tot[STEPS];
    const int tid = threadIdx.x;
    if (tid < NW * HPAD) hist[tid] = 0;
    __syncthreads();

    const int lane = tid & 63;
    const int wave = tid >> 6;
    const int bc = blockIdx.x;
    const float* img = x + (size_t)bc * (HH * WW);
    int* wh = hist + wave * HPAD;
    const float INF = __builtin_huge_valf();

    if (lane < 56) {
        const int j0 = lane * 4;              // pixels (i, j0..j0+3)
        const bool hasL = (j0 > 0), hasR = (j0 + 4 < WW);
        const int i0 = wave * ROWS_PER_WAVE;  // rows i0 .. i0+13
        float mm[6], cm[6], pm[6];            // up / center / down row windows

        if (i0 > 0) {  // wave>0: load row i0-1
            const float* rm = img + (i0 - 1) * WW;
            const float4 t = *(const float4*)(rm + j0);
            mm[0] = hasL ? rm[j0 - 1] : INF;
            mm[1] = t.x; mm[2] = t.y; mm[3] = t.z; mm[4] = t.w;
            mm[5] = hasR ? rm[j0 + 4] : INF;
        } else {
            #pragma unroll
            for (int c = 0; c < 6; ++c) mm[c] = INF;
        }
        {
            const float* rc = img + i0 * WW;
            const float4 t = *(const float4*)(rc + j0);
            cm[0] = hasL ? rc[j0 - 1] : INF;
            cm[1] = t.x; cm[2] = t.y; cm[3] = t.z; cm[4] = t.w;
            cm[5] = hasR ? rc[j0 + 4] : INF;
        }

        for (int r = 0; r < ROWS_PER_WAVE; ++r) {
            const int i = i0 + r;
            if (i + 1 < HH) {  // wave-uniform branch (only last row of image)
                const float* rp = img + (i + 1) * WW;
                const float4 t = *(const float4*)(rp + j0);
                pm[0] = hasL ? rp[j0 - 1] : INF;
                pm[1] = t.x; pm[2] = t.y; pm[3] = t.z; pm[4] = t.w;
                pm[5] = hasR ? rp[j0 + 4] : INF;
            } else {
                #pragma unroll
                for (int c = 0; c < 6; ++c) pm[c] = INF;
            }

            #pragma unroll
            for (int c = 0; c < 4; ++c) {
                const float v = cm[c + 1];
                // earlier neighbors (strict <): UL, U, UR, L
                const bool bUL = v < mm[c];
                const bool bU  = v < mm[c + 1];
                const bool bUR = v < mm[c + 2];
                const bool bL  = v < cm[c];
                // later neighbors (<=): R, DL, D, DR
                const bool bR  = v <= cm[c + 2];
                const bool bDL = v <= pm[c];
                const bool bD  = v <= pm[c + 1];
                const bool bDR = v <= pm[c + 2];
                const int nE = (int)bU + (int)bL + (int)bR + (int)bD;
                const int nV = (int)(bUL & bU & bL) + (int)(bU & bUR & bR) +
                               (int)(bL & bDL & bD) + (int)(bR & bD & bDR);
                const int d = 1 + nV - nE;
                const int k = bin_of(v);
                if (d != 0 && k < STEPS) atomicAdd(&wh[k], d);
            }
            #pragma unroll
            for (int c = 0; c < 6; ++c) { mm[c] = cm[c]; cm[c] = pm[c]; }
        }
    }
    __syncthreads();

    if (tid < STEPS) {
        int s = 0;
        #pragma unroll
        for (int h = 0; h < NW; ++h) s += hist[h * HPAD + tid];
        tot[tid] = s;
    }
    __syncthreads();
    if (tid < STEPS) {
        int acc = 0;
        for (int j = 0; j <= tid; ++j) acc += tot[j];
        out[bc * STEPS + tid] = (float)acc;
    }
}

extern "C" void kernel_launch(void* const* d_in, const int* in_sizes, int n_in,
                              void* d_out, int out_size, void* d_ws, size_t ws_size,
                              hipStream_t stream) {
    const float* x = (const float*)d_in[0];
    float* out = (float*)d_out;
    (void)d_ws; (void)ws_size;

    ecc_all<<<NBC, 1024, 0, stream>>>(x, out);
}

// Round 5
// 59.519 us; speedup vs baseline: 1.1743x; 1.1743x over previous
//
#include <hip/hip_runtime.h>

// CubicalEcc: x [8,3,224,224] f32 -> ecc [8,3,32] f32
// Per-pixel Euler increment: every cell (vertex/edge/face) is owned by its
// argmin incident pixel (ties by row-major memory order; exact with ties).
// chi(t) = sum_p [v_p <= t] * delta_p,  delta_p = 1 + nV(p) - nE(p).
// "p beats q": v_p < v_q if q earlier in row-major order, v_p <= v_q if later;
// out-of-image q = +inf.
// ONE wide kernel (336 blocks): per-wave LDS signed histograms -> block
// prefix-sum -> float atomicAdd of 32 partial ECC values into d_out.
// Integer-valued float adds are exact & order-independent (< 2^24).
// d_out is poisoned by the harness -> zero it with a memset node first.

#define HH 224
#define WW 224
#define STEPS 32
#define NBC 24    // 8*3 images
#define RBLK 14   // blocks per image; each covers 16 pixel rows (4 waves x 4)
#define HPAD 33   // hist stride: spreads bin k of wave w across banks

// smallest k in [0,32) with v <= t_k, t_k = -2 + k*(4/31); 32 => never counted
__device__ __forceinline__ int bin_of(float v) {
    int k = (int)ceilf(fmaf(v, 7.75f, 15.5f));  // (v+2)*31/4
    return max(0, min(32, k));
}

__global__ __launch_bounds__(256) void ecc_hist(const float* __restrict__ x,
                                                float* __restrict__ out) {
    __shared__ int hist[4 * HPAD];
    __shared__ int tot[STEPS];
    const int tid = threadIdx.x;
    if (tid < 4 * HPAD) hist[tid] = 0;
    __syncthreads();

    const int lane = tid & 63;
    const int wave = tid >> 6;
    const int bc = blockIdx.y;
    const float* img = x + (size_t)bc * (HH * WW);
    int* wh = hist + wave * HPAD;
    const float INF = __builtin_huge_valf();

    if (lane < 56) {
        const int j0 = lane * 4;  // pixels (i, j0..j0+3)
        const bool hasL = (j0 > 0), hasR = (j0 + 4 < WW);
        const int i0 = blockIdx.x * 16 + wave * 4;  // rows i0..i0+3 (< 224)
        float mm[6], cm[6], pm[6];  // up / center / down row windows

        if (i0 > 0) {
            const float* rm = img + (i0 - 1) * WW;
            const float4 t = *(const float4*)(rm + j0);
            mm[0] = hasL ? rm[j0 - 1] : INF;
            mm[1] = t.x; mm[2] = t.y; mm[3] = t.z; mm[4] = t.w;
            mm[5] = hasR ? rm[j0 + 4] : INF;
        } else {
            #pragma unroll
            for (int c = 0; c < 6; ++c) mm[c] = INF;
        }
        {
            const float* rc = img + i0 * WW;
            const float4 t = *(const float4*)(rc + j0);
            cm[0] = hasL ? rc[j0 - 1] : INF;
            cm[1] = t.x; cm[2] = t.y; cm[3] = t.z; cm[4] = t.w;
            cm[5] = hasR ? rc[j0 + 4] : INF;
        }

        #pragma unroll
        for (int r = 0; r < 4; ++r) {
            const int i = i0 + r;
            if (i + 1 < HH) {  // wave-uniform (false only for the last row)
                const float* rp = img + (i + 1) * WW;
                const float4 t = *(const float4*)(rp + j0);
                pm[0] = hasL ? rp[j0 - 1] : INF;
                pm[1] = t.x; pm[2] = t.y; pm[3] = t.z; pm[4] = t.w;
                pm[5] = hasR ? rp[j0 + 4] : INF;
            } else {
                #pragma unroll
                for (int c = 0; c < 6; ++c) pm[c] = INF;
            }

            #pragma unroll
            for (int c = 0; c < 4; ++c) {
                const float v = cm[c + 1];
                // earlier neighbors (strict <): UL, U, UR, L
                const bool bUL = v < mm[c];
                const bool bU  = v < mm[c + 1];
                const bool bUR = v < mm[c + 2];
                const bool bL  = v < cm[c];
                // later neighbors (<=): R, DL, D, DR
                const bool bR  = v <= cm[c + 2];
                const bool bDL = v <= pm[c];
                const bool bD  = v <= pm[c + 1];
                const bool bDR = v <= pm[c + 2];
                const int nE = (int)bU + (int)bL + (int)bR + (int)bD;
                const int nV = (int)(bUL & bU & bL) + (int)(bU & bUR & bR) +
                               (int)(bL & bDL & bD) + (int)(bR & bD & bDR);
                const int d = 1 + nV - nE;
                const int k = bin_of(v);
                if (d != 0 && k < STEPS) atomicAdd(&wh[k], d);
            }
            #pragma unroll
            for (int c = 0; c < 6; ++c) { mm[c] = cm[c]; cm[c] = pm[c]; }
        }
    }
    __syncthreads();

    if (tid < STEPS) {
        tot[tid] = hist[tid] + hist[HPAD + tid] +
                   hist[2 * HPAD + tid] + hist[3 * HPAD + tid];
    }
    __syncthreads();
    if (tid < STEPS) {
        int acc = 0;
        for (int j = 0; j <= tid; ++j) acc += tot[j];
        atomicAdd(&out[bc * STEPS + tid], (float)acc);
    }
}

extern "C" void kernel_launch(void* const* d_in, const int* in_sizes, int n_in,
                              void* d_out, int out_size, void* d_ws, size_t ws_size,
                              hipStream_t stream) {
    const float* x = (const float*)d_in[0];
    float* out = (float*)d_out;
    (void)d_ws; (void)ws_size;

    hipMemsetAsync(out, 0, (size_t)NBC * STEPS * sizeof(float), stream);
    ecc_hist<<<dim3(RBLK, NBC), 256, 0, stream>>>(x, out);
}